// Round 6
// baseline (126.081 us; speedup 1.0000x reference)
//
#include <hip/hip_runtime.h>
#include <math.h>

// Fused: out[b,oc,y,x] = max_{dy,dx} min(xmax[b,y+dy-2,x+dx-2], k[oc,dy,dx])
// xmax = channel-max over C=32; OOB = -inf.
// One block = one 32x32 output tile, all 32 oc.
// Phase 1: channel-max of 36x40 halo tile -> LDS (rows padded to 44 floats).
// Phase 2: wave = 8 oc (taps via s_load, wave-uniform); lane = 8px x 2 rows;
//          window (6 rows x 12 floats = 72 VGPR) LDS-read ONCE, reused 8 oc.

#define BATCH 16
#define CH    32
#define OCH   32
#define HH    256
#define WW    256
#define HWSZ  (HH * WW)
#define TW    32
#define TH    32
#define LW    44              // padded LDS row stride (floats); cols 0..39 used
#define LH    36
#define NWG   (BATCH * (WW / TW) * (HH / TH))   // 1024

__device__ __forceinline__ float vmax3(float a, float b, float c) {
    float d;
    asm("v_max3_f32 %0, %1, %2, %3" : "=v"(d) : "v"(a), "v"(b), "v"(c));
    return d;
}

__global__ __launch_bounds__(256, 4) void fused_maxmin_kernel(const float* __restrict__ x,
                                                              const float* __restrict__ kk,
                                                              float* __restrict__ out) {
    __shared__ float xmt[LH][LW];      // channel-max halo tile, -inf at OOB
    int tid = threadIdx.x;
    int bid = blockIdx.x;
    int swz = (bid & 7) * (NWG >> 3) + (bid >> 3);   // XCD-chunked, bijective
    int b   = swz >> 6;
    int ty  = (swz >> 3) & 7;
    int tx  = swz & 7;

    const float NI = -INFINITY;
    int x4base = tx * 8 - 1;           // first float4 col (global)
    int ybase  = ty * 32 - 2;          // first row (global)
    const float4* xb = (const float4*)(x + (size_t)b * CH * HWSZ);

    // ---- Phase 1: channel max into LDS (360 float4 positions) ----
    for (int p = tid; p < 10 * LH; p += 256) {
        int pc = p % 10;
        int pr = p / 10;
        int c4 = x4base + pc;
        int rg = ybase + pr;
        bool valid = (c4 >= 0) && (c4 < WW / 4) && (rg >= 0) && (rg < HH);
        int c4c = c4 < 0 ? 0 : (c4 > WW / 4 - 1 ? WW / 4 - 1 : c4);
        int rgc = rg < 0 ? 0 : (rg > HH - 1 ? HH - 1 : rg);
        const float4* src = xb + (size_t)rgc * (WW / 4) + c4c;
        float4 m = src[0];
#pragma unroll
        for (int c = 1; c < CH; ++c) {
            float4 v = src[(size_t)c * (HWSZ / 4)];
            m.x = fmaxf(m.x, v.x);
            m.y = fmaxf(m.y, v.y);
            m.z = fmaxf(m.z, v.z);
            m.w = fmaxf(m.w, v.w);
        }
        if (!valid) { m.x = NI; m.y = NI; m.z = NI; m.w = NI; }
        *(float4*)&xmt[pr][pc * 4] = m;
    }
    __syncthreads();

    // ---- Phase 2 ----
    int xg  = tid & 3;                               // 4 groups x 8 px
    int rw  = (tid >> 2) & 15;                       // 16 groups x 2 rows
    int wid = __builtin_amdgcn_readfirstlane(tid >> 6);  // wave -> 8 oc (uniform)

    // Window: tile rows 2rw..2rw+5, tile cols 8xg+2..8xg+13 (12 wide).
    float w[6][12];
    {
        const float* wb = &xmt[2 * rw][8 * xg + 2];
#pragma unroll
        for (int r = 0; r < 6; ++r) {
            const float* rp = wb + r * LW;
            *(float2*)&w[r][0]  = *(const float2*)(rp + 0);   // 8B-aligned
            *(float4*)&w[r][2]  = *(const float4*)(rp + 2);   // 16B-aligned
            *(float4*)&w[r][6]  = *(const float4*)(rp + 6);   // 16B-aligned
            *(float2*)&w[r][10] = *(const float2*)(rp + 10);
        }
    }

    size_t obase = (size_t)(b * OCH + wid * 8) * HWSZ
                 + (size_t)(ty * TH + 2 * rw) * WW + tx * TW + 8 * xg;

#pragma unroll 2
    for (int o = 0; o < 8; ++o) {
        const float* kw = kk + (wid * 8 + o) * 25;   // scalar pointer -> s_load
        float kr[25];
#pragma unroll
        for (int i = 0; i < 25; ++i) kr[i] = kw[i];

        float* op = out + obase + (size_t)o * HWSZ;
#pragma unroll
        for (int ry = 0; ry < 2; ++ry) {
            float a[8];
#pragma unroll
            for (int jj = 0; jj < 8; ++jj) {
                float m[25];
#pragma unroll
                for (int dy = 0; dy < 5; ++dy)
#pragma unroll
                    for (int dx = 0; dx < 5; ++dx)
                        m[dy * 5 + dx] = fminf(w[ry + dy][jj + dx], kr[dy * 5 + dx]);
                float t0 = vmax3(m[0],  m[1],  m[2]);
                float t1 = vmax3(m[3],  m[4],  m[5]);
                float t2 = vmax3(m[6],  m[7],  m[8]);
                float t3 = vmax3(m[9],  m[10], m[11]);
                float t4 = vmax3(m[12], m[13], m[14]);
                float t5 = vmax3(m[15], m[16], m[17]);
                float t6 = vmax3(m[18], m[19], m[20]);
                float t7 = vmax3(m[21], m[22], m[23]);
                float u0 = vmax3(t0, t1, t2);
                float u1 = vmax3(t3, t4, t5);
                float u2 = vmax3(t6, t7, m[24]);
                a[jj] = vmax3(u0, u1, u2);
            }
            *(float4*)(op + ry * WW + 0) = make_float4(a[0], a[1], a[2], a[3]);
            *(float4*)(op + ry * WW + 4) = make_float4(a[4], a[5], a[6], a[7]);
        }
    }
}

extern "C" void kernel_launch(void* const* d_in, const int* in_sizes, int n_in,
                              void* d_out, int out_size, void* d_ws, size_t ws_size,
                              hipStream_t stream) {
    const float* x  = (const float*)d_in[0];
    const float* kk = (const float*)d_in[1];
    float* out      = (float*)d_out;
    fused_maxmin_kernel<<<NWG, 256, 0, stream>>>(x, kk, out);
}

// Round 8
// 55.403 us; speedup vs baseline: 2.2757x; 2.2757x over previous
//
#include <hip/hip_runtime.h>
#include <math.h>

// Fused: out[b,oc,y,x] = max_{dy,dx} min(xmax[b,y+dy-2,x+dx-2], k[oc,dy,dx])
// xmax = channel-max over C=32; OOB = -inf.
// x (16,32,256,256) f32, k (32,5,5) f32, out (16,32,256,256) f32.
//
// One block = 32x16 output tile, all 32 oc. 2048 blocks (8/CU, ~4 resident ->
// next-generation phase1 reads overlap resident blocks' phase2 compute/write).
// Phase 1: channel-max of 20x40 halo tile (origin x0-4,y0-2) -> LDS, -inf OOB.
// Phase 2: wave = 8 oc (taps s_load, wave-uniform); lane = 4px x 2rows;
//          window 6x8 floats (48 VGPR) via ds_read_b64, reused across 8 oc.
// Output via nontemporal stores (never re-read; keeps input LLC-resident).

#define BATCH 16
#define CH    32
#define OCH   32
#define HH    256
#define WW    256
#define HWSZ  (HH * WW)
#define TW    32
#define TH    16
#define LH    20              // TH + 4
#define LW    42              // stride: 40 data cols + 2 pad; rows 8B-aligned
#define NWG   (BATCH * (HH / TH) * (WW / TW))   // 2048

typedef float floatx4 __attribute__((ext_vector_type(4)));   // native vec for nt-store

__device__ __forceinline__ float vmax3(float a, float b, float c) {
    float d;
    asm("v_max3_f32 %0, %1, %2, %3" : "=v"(d) : "v"(a), "v"(b), "v"(c));
    return d;
}

__global__ __launch_bounds__(256, 2) void fused_maxmin_kernel(const float* __restrict__ x,
                                                              const float* __restrict__ kk,
                                                              float* __restrict__ out) {
    __shared__ float xmt[LH][LW];
    int tid = threadIdx.x;
    int bid = blockIdx.x;
    int swz = (bid & 7) * (NWG >> 3) + (bid >> 3);   // XCD-chunked, bijective (2048%8==0)
    int b   = swz >> 7;                              // 128 tiles/batch
    int t2  = swz & 127;
    int ty  = t2 >> 3;                               // 0..15
    int tx  = t2 & 7;                                // 0..7

    const float NI = -INFINITY;

    // ---- Phase 1: channel max of 20 rows x 10 float4 granules ----
    if (tid < 200) {
        int pr = tid / 10;                           // LDS row 0..19
        int pc = tid % 10;                           // granule 0..9
        int c4 = tx * 8 - 1 + pc;                    // global float4 col
        int rw = ty * TH - 2 + pr;                   // global row
        bool valid = (c4 >= 0) && (c4 < WW / 4) && (rw >= 0) && (rw < HH);
        int c4c = c4 < 0 ? 0 : (c4 > WW / 4 - 1 ? WW / 4 - 1 : c4);
        int rwc = rw < 0 ? 0 : (rw > HH - 1 ? HH - 1 : rw);
        const float4* src = (const float4*)x + (size_t)b * CH * (HWSZ / 4)
                          + (size_t)rwc * (WW / 4) + c4c;
        float4 m = src[0];
#pragma unroll
        for (int c = 1; c < CH; ++c) {
            float4 v = src[(size_t)c * (HWSZ / 4)];
            m.x = fmaxf(m.x, v.x);
            m.y = fmaxf(m.y, v.y);
            m.z = fmaxf(m.z, v.z);
            m.w = fmaxf(m.w, v.w);
        }
        if (!valid) { m.x = NI; m.y = NI; m.z = NI; m.w = NI; }
        *(float2*)&xmt[pr][4 * pc]     = make_float2(m.x, m.y);   // stride 42 -> 8B align
        *(float2*)&xmt[pr][4 * pc + 2] = make_float2(m.z, m.w);
    }
    __syncthreads();

    // ---- Phase 2 ----
    int xg = tid & 7;                                // 8 groups x 4 px
    int rg = (tid >> 3) & 7;                         // 8 groups x 2 rows
    int wv = __builtin_amdgcn_readfirstlane(tid >> 6);   // wave -> oc 8*wv..8*wv+7

    // Window: LDS rows 2rg..2rg+5, cols 4xg+2..4xg+9 (8B-aligned float2 reads).
    float w[6][8];
#pragma unroll
    for (int r = 0; r < 6; ++r) {
        const float* rp = &xmt[2 * rg + r][4 * xg + 2];
#pragma unroll
        for (int s = 0; s < 4; ++s)
            *(float2*)&w[r][2 * s] = *(const float2*)(rp + 2 * s);
    }

    size_t obase = (size_t)(b * OCH + wv * 8) * HWSZ
                 + (size_t)(ty * TH + 2 * rg) * WW + tx * TW + 4 * xg;

    for (int o = 0; o < 8; ++o) {
        const float* kw = kk + (wv * 8 + o) * 25;    // wave-uniform -> s_load
        float kr[25];
#pragma unroll
        for (int i = 0; i < 25; ++i) kr[i] = kw[i];

        float* op = out + obase + (size_t)o * HWSZ;
#pragma unroll
        for (int r = 0; r < 2; ++r) {
            float a[4];
#pragma unroll
            for (int j = 0; j < 4; ++j) {
                float m[25];
#pragma unroll
                for (int dy = 0; dy < 5; ++dy)
#pragma unroll
                    for (int dx = 0; dx < 5; ++dx)
                        m[dy * 5 + dx] = fminf(w[r + dy][j + dx], kr[dy * 5 + dx]);
                float t0 = vmax3(m[0],  m[1],  m[2]);
                float t1 = vmax3(m[3],  m[4],  m[5]);
                float t2 = vmax3(m[6],  m[7],  m[8]);
                float t3 = vmax3(m[9],  m[10], m[11]);
                float t4 = vmax3(m[12], m[13], m[14]);
                float t5 = vmax3(m[15], m[16], m[17]);
                float t6 = vmax3(m[18], m[19], m[20]);
                float t7 = vmax3(m[21], m[22], m[23]);
                float u0 = vmax3(t0, t1, t2);
                float u1 = vmax3(t3, t4, t5);
                float u2 = vmax3(t6, t7, m[24]);
                a[j] = vmax3(u0, u1, u2);
            }
            floatx4 ov = { a[0], a[1], a[2], a[3] };
            __builtin_nontemporal_store(ov, (floatx4*)(op + (size_t)r * WW));
        }
    }
}

extern "C" void kernel_launch(void* const* d_in, const int* in_sizes, int n_in,
                              void* d_out, int out_size, void* d_ws, size_t ws_size,
                              hipStream_t stream) {
    const float* x  = (const float*)d_in[0];
    const float* kk = (const float*)d_in[1];
    float* out      = (float*)d_out;
    fused_maxmin_kernel<<<NWG, 256, 0, stream>>>(x, kk, out);
}